// Round 1
// baseline (73.142 us; speedup 1.0000x reference)
//
#include <hip/hip_runtime.h>

#define Bdim   4096
#define INdim  4096
#define OUTdim 2048
#define Knz    32

// f32 -> bf16 round-to-nearest-even
__device__ inline unsigned short f2bf(float f) {
  unsigned u = __float_as_uint(f);
  u += 0x7fffu + ((u >> 16) & 1u);
  return (unsigned short)(u >> 16);
}

// Kernel 1: xT[i][b] = bf16(x[b][i]).  64x64 tiles via LDS.
__global__ __launch_bounds__(256) void k_transpose(const float* __restrict__ x,
                                                   unsigned short* __restrict__ xT) {
  __shared__ float tile[64][65];  // +1 pad: read phase lands 2-way (free) on banks
  const int bi = blockIdx.x;      // 64-row tile of x (b dim)
  const int ii = blockIdx.y;      // 64-col tile of x (IN dim)
  const int t = threadIdx.x;
  const int r = t >> 4;           // 0..15
  const int c = t & 15;           // 0..15 (16B column group)
#pragma unroll
  for (int rr = 0; rr < 64; rr += 16) {
    const float4 v = *reinterpret_cast<const float4*>(
        &x[(size_t)(bi * 64 + rr + r) * INdim + ii * 64 + c * 4]);
    tile[rr + r][c * 4 + 0] = v.x;
    tile[rr + r][c * 4 + 1] = v.y;
    tile[rr + r][c * 4 + 2] = v.z;
    tile[rr + r][c * 4 + 3] = v.w;
  }
  __syncthreads();
#pragma unroll
  for (int rr = 0; rr < 64; rr += 16) {
    const int il = rr + r;        // IN-local row of xT
    ushort4 o;
    o.x = f2bf(tile[c * 4 + 0][il]);
    o.y = f2bf(tile[c * 4 + 1][il]);
    o.z = f2bf(tile[c * 4 + 2][il]);
    o.w = f2bf(tile[c * 4 + 3][il]);
    *reinterpret_cast<ushort4*>(
        &xT[(size_t)(ii * 64 + il) * Bdim + bi * 64 + c * 4]) = o;
  }
}

// Kernel 2: gather-dot. Each thread owns 2 consecutive b and 8 outputs.
// grid = 2048 blocks: bb = wg&7 (XCD-pinned: 4MB xT slice per XCD L2),
// ob = wg>>3 in [0,256).
__global__ __launch_bounds__(256) void k_gather(const unsigned short* __restrict__ xT,
                                                const int* __restrict__ cols,
                                                const float* __restrict__ values,
                                                float* __restrict__ out) {
  const int wg = blockIdx.x;
  const int bb = wg & 7;
  const int ob = wg >> 3;
  const int t = threadIdx.x;
  const int b0 = bb * 512 + t * 2;    // two consecutive b per thread
  const int obase = ob * 8;

  float acc0[8], acc1[8];
#pragma unroll
  for (int oc = 0; oc < 8; ++oc) {
    const int o = obase + oc;
    const int* __restrict__ cp = cols + o * Knz;
    const float* __restrict__ vp = values + o * Knz;
    float a0 = 0.f, a1 = 0.f;
#pragma unroll
    for (int k = 0; k < Knz; ++k) {
      const int col = cp[k];      // uniform -> scalar load
      const float val = vp[k];    // uniform -> scalar load
      const unsigned u = *reinterpret_cast<const unsigned*>(
          &xT[(size_t)col * Bdim + b0]);            // coalesced 4B/lane
      const float x0 = __uint_as_float(u << 16);          // low bf16
      const float x1 = __uint_as_float(u & 0xffff0000u);  // high bf16
      a0 = fmaf(x0, val, a0);
      a1 = fmaf(x1, val, a1);
    }
    acc0[oc] = a0;
    acc1[oc] = a1;
  }
  // 32B-contiguous stores per lane per row
  float4* p0 = reinterpret_cast<float4*>(&out[(size_t)b0 * OUTdim + obase]);
  float4* p1 = reinterpret_cast<float4*>(&out[(size_t)(b0 + 1) * OUTdim + obase]);
  p0[0] = make_float4(acc0[0], acc0[1], acc0[2], acc0[3]);
  p0[1] = make_float4(acc0[4], acc0[5], acc0[6], acc0[7]);
  p1[0] = make_float4(acc1[0], acc1[1], acc1[2], acc1[3]);
  p1[1] = make_float4(acc1[4], acc1[5], acc1[6], acc1[7]);
}

// Correct-but-slow fallback if ws can't hold xT (32 MB).
__global__ __launch_bounds__(256) void k_naive(const float* __restrict__ x,
                                               const float* __restrict__ values,
                                               const int* __restrict__ cols,
                                               float* __restrict__ out) {
  const size_t id = (size_t)blockIdx.x * 256 + threadIdx.x;
  const int o = (int)(id % OUTdim);
  const int b = (int)(id / OUTdim);
  float a = 0.f;
  for (int k = 0; k < Knz; ++k) {
    const int col = cols[o * Knz + k];
    a = fmaf(x[(size_t)b * INdim + col], values[o * Knz + k], a);
  }
  out[id] = a;
}

extern "C" void kernel_launch(void* const* d_in, const int* in_sizes, int n_in,
                              void* d_out, int out_size, void* d_ws, size_t ws_size,
                              hipStream_t stream) {
  const float* x = (const float*)d_in[0];
  const float* values = (const float*)d_in[1];
  const int* cols = (const int*)d_in[2];
  float* out = (float*)d_out;

  const size_t need = (size_t)INdim * Bdim * sizeof(unsigned short);  // 32 MB
  if (ws_size >= need) {
    unsigned short* xT = (unsigned short*)d_ws;
    k_transpose<<<dim3(64, 64), 256, 0, stream>>>(x, xT);
    k_gather<<<2048, 256, 0, stream>>>(xT, cols, values, out);
  } else {
    k_naive<<<(Bdim * (size_t)OUTdim) / 256, 256, 0, stream>>>(x, values, cols, out);
  }
}